// Round 9
// baseline (160.796 us; speedup 1.0000x reference)
//
#include <hip/hip_runtime.h>
#include <hip/hip_bf16.h>

// DilatedMSA round 14: r13 base + attention-loop pipeline restructure.
//  GEMM phase identical to r13 (proven hidden). Attention changes:
//   - ni-interleave: QK(ni0)+QK(ni1) issued back-to-back (independent MFMA
//     chains), then both softmaxes, then all 8 PV MFMAs.
//   - strip-ahead K/V prefetch: double-buffered kf/vf register sets; next
//     strip's 8 ds_reads issue right after QK consumes the current kf, so
//     LDS latency hides under softmax+PV (r13 stalled ~150cy at strip head).
//   - tree-sum for softmax denominator (depth 4 vs 16-serial adds).
//  Keeps: stagger (r13's only proven win), exp2f builtin, setprio clusters,
//  in-register P via cvt_pk + permlane32_swap, one barrier.

typedef __bf16 bf16x8 __attribute__((ext_vector_type(8)));
typedef float  f32x4  __attribute__((ext_vector_type(4)));
typedef float  f32x16 __attribute__((ext_vector_type(16)));

#define MFMA16(a, b, c) __builtin_amdgcn_mfma_f32_16x16x32_bf16((a), (b), (c), 0, 0, 0)
#define MFMA32(a, b, c) __builtin_amdgcn_mfma_f32_32x32x16_bf16((a), (b), (c), 0, 0, 0)

namespace dmsa {

constexpr int G  = 256;    // tokens per (b,l)
constexpr int C  = 128;    // channels
constexpr int HD = 64;     // head dim
// fold log2(e)/sqrt(128) into Q -> attn does exp2(s) directly
constexpr float QSCALE = 1.4426950408889634f * 0.08838834764831845f;

__device__ __forceinline__ unsigned pack2(float a, float b) {
    union { __hip_bfloat162 h; unsigned u; } c;
    c.h = __float22bfloat162_rn(make_float2(a, b));   // v_cvt_pk_bf16_f32
    return c.u;
}
__device__ __forceinline__ uint2 pack4(float a, float b, float c, float d) {
    uint2 r; r.x = pack2(a, b); r.y = pack2(c, d); return r;
}
__device__ __forceinline__ uint4 pack8(const float* p) {
    uint4 r;
    r.x = pack2(p[0], p[1]); r.y = pack2(p[2], p[3]);
    r.z = pack2(p[4], p[5]); r.w = pack2(p[6], p[7]);
    return r;
}
__device__ __forceinline__ bf16x8 lds8(const ushort* p) { return *(const bf16x8*)p; }
__device__ __forceinline__ bf16x8 ldg8(const ushort* p) { return *(const bf16x8*)p; }
// 8 consecutive fp32 -> bf16x8 fragment
__device__ __forceinline__ bf16x8 ld8f(const float* __restrict__ p) {
    float t[8];
    *(float4*)t       = *(const float4*)p;
    *(float4*)(t + 4) = *(const float4*)(p + 4);
    union { uint4 u; bf16x8 v; } c;
    c.u = pack8(t);
    return c.v;
}

// ---------------------------------------------------------------------------
// K0: W [384][128] fp32 -> bf16.
// ---------------------------------------------------------------------------
__global__ void convw(const float* __restrict__ W, ushort* __restrict__ wbf) {
    int t = blockIdx.x * 256 + threadIdx.x;
    float tmp[8];
    const float* p = W + (size_t)t * 8;
    *(float4*)tmp       = *(const float4*)p;
    *(float4*)(tmp + 4) = *(const float4*)(p + 4);
    *(uint4*)(wbf + (size_t)t * 8) = pack8(tmp);
}

// ---------------------------------------------------------------------------
// K1: grid 1024 = (bl 512) x (h 2), block 256 (4 waves).
// Wave wv owns tokens/queries wv*64..+64 for the GEMMs and attention.
// ---------------------------------------------------------------------------
__global__ __launch_bounds__(256, 2)
void fused(const float* __restrict__ x, const ushort* __restrict__ wb,
           const float* __restrict__ bias, float* __restrict__ out)
{
    __shared__ ushort kc[G * 72];        // K [256 g][64 c' +pad8]; Q-stage first
    __shared__ ushort vc[HD * 264];      // V^T [64 c'][256 g +pad8]

    const int tid = threadIdx.x, wv = tid >> 6, lane = tid & 63;
    const int l16 = lane & 15, quad = lane >> 4;
    const int l32 = lane & 31, hl = lane >> 5;

    // XCD-chunked bijective swizzle (1024 % 8 == 0): h=0/1 of one bl colocate.
    const int b  = blockIdx.x;
    const int L  = ((b & 7) << 7) | (b >> 3);
    const int bl = L >> 1, h = L & 1;

    const float*  xr = x  + (size_t)bl * G * C;
    const ushort* Wq = wb + (size_t)(h * HD) * C;
    const ushort* Wk = wb + (size_t)(C + h * HD) * C;
    const ushort* Wv = wb + (size_t)(2 * C + h * HD) * C;

    const int r0 = wv * 64;
    const f32x4 z4 = {0.f, 0.f, 0.f, 0.f};

    // ---- x fragments: fp32 -> bf16 ONCE, reused by Q(B), K(B), V(A) GEMMs.
    bf16x8 xf[4][4];   // [16-row tile][32-ch chunk]
    #pragma unroll
    for (int i = 0; i < 4; ++i)
        #pragma unroll
        for (int kk = 0; kk < 4; ++kk)
            xf[i][kk] = ld8f(xr + (size_t)(r0 + i * 16 + l16) * C + kk * 32 + quad * 8);

    // ---- Q-GEMM: Q^T [c'][q]. A=Wq (m=c', 4 tiles), B=xf.
    f32x4 qacc[4][4];
    #pragma unroll
    for (int mi = 0; mi < 4; ++mi)
        #pragma unroll
        for (int ni = 0; ni < 4; ++ni) qacc[mi][ni] = z4;
    #pragma unroll
    for (int kk = 0; kk < 4; ++kk)
        #pragma unroll
        for (int mi = 0; mi < 4; ++mi) {
            bf16x8 a = ldg8(Wq + (size_t)(mi * 16 + l16) * C + kk * 32 + quad * 8);
            #pragma unroll
            for (int ni = 0; ni < 4; ++ni)
                qacc[mi][ni] = MFMA16(a, xf[ni][kk], qacc[mi][ni]);
        }
    // stage to wave-private kc slice (+bias, *QSCALE): qs[q][c']
    ushort* qs = kc + r0 * 72;
    #pragma unroll
    for (int mi = 0; mi < 4; ++mi) {
        float4 bs = *(const float4*)(bias + h * HD + mi * 16 + quad * 4);
        #pragma unroll
        for (int ni = 0; ni < 4; ++ni)
            *(uint2*)(qs + (ni * 16 + l16) * 72 + mi * 16 + quad * 4) =
                pack4((qacc[mi][ni][0] + bs.x) * QSCALE,
                      (qacc[mi][ni][1] + bs.y) * QSCALE,
                      (qacc[mi][ni][2] + bs.z) * QSCALE,
                      (qacc[mi][ni][3] + bs.w) * QSCALE);
    }
    // read back as 32x32x16 B-frags: B[n=q=l32][k=c' chunk kk*16+hl*8]
    bf16x8 qf[2][4];
    #pragma unroll
    for (int ni = 0; ni < 2; ++ni)
        #pragma unroll
        for (int kk = 0; kk < 4; ++kk)
            qf[ni][kk] = lds8(qs + (ni * 32 + l32) * 72 + kk * 16 + hl * 8);

    // ---- K-GEMM: A=Wk (m=c'), B=xf. Epi overwrites own kc slice.
    {
        f32x4 kacc[4][4];
        #pragma unroll
        for (int mi = 0; mi < 4; ++mi)
            #pragma unroll
            for (int nt = 0; nt < 4; ++nt) kacc[mi][nt] = z4;
        #pragma unroll
        for (int kk = 0; kk < 4; ++kk)
            #pragma unroll
            for (int mi = 0; mi < 4; ++mi) {
                bf16x8 a = ldg8(Wk + (size_t)(mi * 16 + l16) * C + kk * 32 + quad * 8);
                #pragma unroll
                for (int nt = 0; nt < 4; ++nt)
                    kacc[mi][nt] = MFMA16(a, xf[nt][kk], kacc[mi][nt]);
            }
        // C/D col=g=l16, row=c' -> kc[g][c']
        #pragma unroll
        for (int mi = 0; mi < 4; ++mi) {
            float4 bs = *(const float4*)(bias + C + h * HD + mi * 16 + quad * 4);
            #pragma unroll
            for (int nt = 0; nt < 4; ++nt)
                *(uint2*)(kc + (r0 + nt * 16 + l16) * 72 + mi * 16 + quad * 4) =
                    pack4(kacc[mi][nt][0] + bs.x, kacc[mi][nt][1] + bs.y,
                          kacc[mi][nt][2] + bs.z, kacc[mi][nt][3] + bs.w);
        }
    }

    // ---- V-GEMM: A=xf (m=tok), B=Wv (n=c'). Epi: disjoint vc columns.
    {
        f32x4 vacc[4][4];
        #pragma unroll
        for (int mt = 0; mt < 4; ++mt)
            #pragma unroll
            for (int nt = 0; nt < 4; ++nt) vacc[mt][nt] = z4;
        #pragma unroll
        for (int kk = 0; kk < 4; ++kk)
            #pragma unroll
            for (int nt = 0; nt < 4; ++nt) {
                bf16x8 bw = ldg8(Wv + (size_t)(nt * 16 + l16) * C + kk * 32 + quad * 8);
                #pragma unroll
                for (int mt = 0; mt < 4; ++mt)
                    vacc[mt][nt] = MFMA16(xf[mt][kk], bw, vacc[mt][nt]);
            }
        // C/D col=c'=l16, row=g -> vc[c'][g]
        #pragma unroll
        for (int nt = 0; nt < 4; ++nt) {
            float bv = bias[2 * C + h * HD + nt * 16 + l16];
            #pragma unroll
            for (int mt = 0; mt < 4; ++mt)
                *(uint2*)(vc + (nt * 16 + l16) * 264 + r0 + mt * 16 + quad * 4) =
                    pack4(vacc[mt][nt][0] + bv, vacc[mt][nt][1] + bv,
                          vacc[mt][nt][2] + bv, vacc[mt][nt][3] + bv);
        }
    }

    __syncthreads();   // K/V tiles ready for all waves (the only barrier)

    // ---- attention, 32x32x16, ni-interleaved + strip-ahead K/V prefetch.
    float lacc[2] = {0.f, 0.f};
    f32x16 oacc[2][2];   // [mt][ni]
    #pragma unroll
    for (int mt = 0; mt < 2; ++mt)
        #pragma unroll
        for (int ni = 0; ni < 2; ++ni)
            #pragma unroll
            for (int r = 0; r < 16; ++r) oacc[mt][ni][r] = 0.f;

    const int spoff = 2 * wv + ((b & 1) << 2);   // stall de-correlation (r13 win)

    bf16x8 kfA[4], vfA[4], kfB[4], vfB[4];       // double-buffered strip frags

    auto ldkv = [&](bf16x8 (&kf)[4], bf16x8 (&vf)[4], int g0) {
        #pragma unroll
        for (int kk = 0; kk < 4; ++kk)
            kf[kk] = lds8(kc + (g0 + l32) * 72 + kk * 16 + hl * 8);
        #pragma unroll
        for (int mt = 0; mt < 2; ++mt)
            #pragma unroll
            for (int ch = 0; ch < 2; ++ch)
                vf[mt * 2 + ch] = lds8(vc + (mt * 32 + l32) * 264 + g0 + ch * 16 + hl * 8);
    };

    // softmax + in-register P pack (cvt_pk + permlane32_swap); tree-sum denom
    auto smx = [&](f32x16& s, float& lsum, bf16x8& pa, bf16x8& pb) {
        #pragma unroll
        for (int r = 0; r < 16; ++r) s[r] = __builtin_amdgcn_exp2f(s[r]);
        float a0 = (s[0] + s[1]) + (s[2] + s[3]);
        float a1 = (s[4] + s[5]) + (s[6] + s[7]);
        float a2 = (s[8] + s[9]) + (s[10] + s[11]);
        float a3 = (s[12] + s[13]) + (s[14] + s[15]);
        lsum += (a0 + a1) + (a2 + a3);
        #pragma unroll
        for (int ch = 0; ch < 2; ++ch) {
            unsigned p0a = pack2(s[8 * ch + 0], s[8 * ch + 1]);
            unsigned p0b = pack2(s[8 * ch + 2], s[8 * ch + 3]);
            unsigned p1a = pack2(s[8 * ch + 4], s[8 * ch + 5]);
            unsigned p1b = pack2(s[8 * ch + 6], s[8 * ch + 7]);
            auto w02 = __builtin_amdgcn_permlane32_swap((int)p0a, (int)p1a, false, false);
            auto w13 = __builtin_amdgcn_permlane32_swap((int)p0b, (int)p1b, false, false);
            union { uint4 u; bf16x8 v; } pf_;
            pf_.u.x = (unsigned)w02[0]; pf_.u.y = (unsigned)w13[0];
            pf_.u.z = (unsigned)w02[1]; pf_.u.w = (unsigned)w13[1];
            if (ch == 0) pa = pf_.v; else pb = pf_.v;
        }
    };

    auto strip = [&](bf16x8 (&kfC)[4], bf16x8 (&vfC)[4],
                     bf16x8 (&kfN)[4], bf16x8 (&vfN)[4],
                     int g0, int gn, bool pf) {
        // QK both ni back-to-back: two independent accumulator chains
        f32x16 s0, s1;
        #pragma unroll
        for (int r = 0; r < 16; ++r) { s0[r] = 0.f; s1[r] = 0.f; }
        __builtin_amdgcn_s_setprio(1);
        #pragma unroll
        for (int kk = 0; kk < 4; ++kk) s0 = MFMA32(kfC[kk], qf[0][kk], s0);
        #pragma unroll
        for (int kk = 0; kk < 4; ++kk) s1 = MFMA32(kfC[kk], qf[1][kk], s1);
        __builtin_amdgcn_s_setprio(0);
        // prefetch next strip's K/V now: latency hides under softmax + PV
        if (pf) ldkv(kfN, vfN, gn);
        bf16x8 p0a, p0b, p1a, p1b;
        smx(s0, lacc[0], p0a, p0b);
        smx(s1, lacc[1], p1a, p1b);
        __builtin_amdgcn_s_setprio(1);
        oacc[0][0] = MFMA32(vfC[0], p0a, oacc[0][0]);
        oacc[0][0] = MFMA32(vfC[1], p0b, oacc[0][0]);
        oacc[1][0] = MFMA32(vfC[2], p0a, oacc[1][0]);
        oacc[1][0] = MFMA32(vfC[3], p0b, oacc[1][0]);
        oacc[0][1] = MFMA32(vfC[0], p1a, oacc[0][1]);
        oacc[0][1] = MFMA32(vfC[1], p1b, oacc[0][1]);
        oacc[1][1] = MFMA32(vfC[2], p1a, oacc[1][1]);
        oacc[1][1] = MFMA32(vfC[3], p1b, oacc[1][1]);
        __builtin_amdgcn_s_setprio(0);
    };

    ldkv(kfA, vfA, (spoff & 7) * 32);
    #pragma unroll 1
    for (int it = 0; it < 4; ++it) {
        const int t = 2 * it;
        strip(kfA, vfA, kfB, vfB,
              ((spoff + t) & 7) * 32, ((spoff + t + 1) & 7) * 32, true);
        strip(kfB, vfB, kfA, vfA,
              ((spoff + t + 1) & 7) * 32, ((spoff + t + 2) & 7) * 32, it < 3);
    }

    // epilogue: out[bl, g, h*64+c']; O^T C/D: col=q=l32, row=c'=4rr..+4hl+32mt
    float* og = out + (size_t)bl * G * C + h * HD;
    #pragma unroll
    for (int ni = 0; ni < 2; ++ni) {
        float l = lacc[ni];
        l += __shfl_xor(l, 32);          // rows split only across lane halves
        float inv = 1.0f / l;
        int g = r0 + ni * 32 + l32;
        #pragma unroll
        for (int mt = 0; mt < 2; ++mt)
            #pragma unroll
            for (int rr = 0; rr < 4; ++rr) {
                float4 st;
                st.x = oacc[mt][ni][4 * rr + 0] * inv;
                st.y = oacc[mt][ni][4 * rr + 1] * inv;
                st.z = oacc[mt][ni][4 * rr + 2] * inv;
                st.w = oacc[mt][ni][4 * rr + 3] * inv;
                *(float4*)(og + (size_t)g * C + mt * 32 + rr * 8 + hl * 4) = st;
            }
    }
}

} // namespace dmsa

extern "C" void kernel_launch(void* const* d_in, const int* in_sizes, int n_in,
                              void* d_out, int out_size, void* d_ws, size_t ws_size,
                              hipStream_t stream) {
    (void)in_sizes; (void)n_in; (void)out_size;

    if (ws_size < (size_t)384 * 128 * 2) return;   // 96 KB W-bf16 scratch

    const float* x    = (const float*)d_in[0];
    const float* W    = (const float*)d_in[1];
    const float* bias = (const float*)d_in[2];
    float* out = (float*)d_out;

    ushort* wbf = (ushort*)d_ws;

    dmsa::convw<<<dim3(24),   dim3(256), 0, stream>>>(W, wbf);
    dmsa::fused<<<dim3(1024), dim3(256), 0, stream>>>(x, wbf, bias, out);
}